// Round 1
// baseline (234.327 us; speedup 1.0000x reference)
//
#include <hip/hip_runtime.h>
#include <cstdint>

#define EPS 1e-5f
#define D_IN 128
#define H_DIM 64
#define R_DIM 32
#define T_HEADS 8

// workspace float offsets
#define WS_TW1S 0        // 16384 floats, layout [(r*64+j)*8 + t]
#define WS_TB1S 16384    // 256, layout [r*8 + t]
#define WS_W2S  16640    // 256, layout [r*8 + t]
#define WS_C2   16896    // 8
#define WS_TOTAL 16904

// Fold both eval-mode BatchNorms into the head weights/biases.
__global__ void tarnet_precompute(
    const float* __restrict__ f_gamma, const float* __restrict__ f_beta,
    const float* __restrict__ f_mean,  const float* __restrict__ f_var,
    const float* __restrict__ tw1,     const float* __restrict__ tb1,
    const float* __restrict__ t_gamma, const float* __restrict__ t_beta,
    const float* __restrict__ t_mean,  const float* __restrict__ t_var,
    const float* __restrict__ tw2,     const float* __restrict__ tb2,
    float* __restrict__ ws)
{
    __shared__ float fs[H_DIM], fsh[H_DIM];
    const int i = threadIdx.x;  // 256 threads
    if (i < H_DIM) {
        float s = f_gamma[i] * rsqrtf(f_var[i] + EPS);
        fs[i]  = s;
        fsh[i] = f_beta[i] - f_mean[i] * s;
    }
    __syncthreads();
    {
        const int t = i & 7, r = i >> 3;          // one (t,r) pair per thread
        const int idx = t * R_DIM + r;            // input layout [T,R]
        float tsc = t_gamma[idx] * rsqrtf(t_var[idx] + EPS);
        float tsh = t_beta[idx] - t_mean[idx] * tsc;
        ws[WS_W2S + r * 8 + t] = tw2[idx] * tsc;
        float acc = tb1[idx];
        for (int j = 0; j < H_DIM; ++j) {
            float w = tw1[idx * H_DIM + j];
            acc += w * fsh[j];
            ws[WS_TW1S + (r * H_DIM + j) * 8 + t] = w * fs[j];
        }
        ws[WS_TB1S + r * 8 + t] = acc;
    }
    if (i < T_HEADS) {
        float a = tb2[i];
        for (int r = 0; r < R_DIM; ++r) {
            const int idx = i * R_DIM + r;
            float tsc = t_gamma[idx] * rsqrtf(t_var[idx] + EPS);
            float tsh = t_beta[idx] - t_mean[idx] * tsc;
            a += tw2[idx] * tsh;
        }
        ws[WS_C2 + i] = a;
    }
}

__global__ __launch_bounds__(256, 2) void tarnet_main(
    const float* __restrict__ x, const int* __restrict__ t,
    const float* __restrict__ fw, const float* __restrict__ fb,
    const float* __restrict__ ws, float* __restrict__ out, int B)
{
    __shared__ float smem[WS_TOTAL];
    for (int idx = threadIdx.x; idx < WS_TOTAL; idx += 256)
        smem[idx] = ws[idx];
    __syncthreads();
    const float* s_tw1s = smem + WS_TW1S;
    const float* s_tb1s = smem + WS_TB1S;
    const float* s_w2s  = smem + WS_W2S;
    const float* s_c2   = smem + WS_C2;

    const int b = blockIdx.x * 256 + threadIdx.x;
    if (b >= B) return;
    const int tt = t[b];

    // x row -> 128 VGPRs (32 x float4)
    float4 xr[32];
    const float4* xq = (const float4*)(x + (size_t)b * D_IN);
#pragma unroll
    for (int q = 0; q < 32; ++q) xr[q] = xq[q];

    float z[R_DIM];
#pragma unroll
    for (int r = 0; r < R_DIM; ++r) z[r] = s_tb1s[r * 8 + tt];

    const float4* fw4 = (const float4*)fw;
#pragma unroll 1
    for (int j = 0; j < H_DIM; ++j) {
        // fw/fb indices are wave-uniform -> compiler emits scalar (s_load) reads
        float h0 = fb[j], h1 = 0.f, h2 = 0.f, h3 = 0.f;
#pragma unroll
        for (int q = 0; q < 32; ++q) {
            float4 w = fw4[j * 32 + q];
            h0 = fmaf(xr[q].x, w.x, h0);
            h1 = fmaf(xr[q].y, w.y, h1);
            h2 = fmaf(xr[q].z, w.z, h2);
            h3 = fmaf(xr[q].w, w.w, h3);
        }
        float hj = fmaxf((h0 + h1) + (h2 + h3), 0.0f);
        // [r][j][t] layout: 8 distinct t's -> 8 consecutive words -> 8 banks, broadcast
#pragma unroll
        for (int r = 0; r < R_DIM; ++r)
            z[r] = fmaf(s_tw1s[(r * H_DIM + j) * 8 + tt], hj, z[r]);
    }

    float acc = s_c2[tt];
#pragma unroll
    for (int r = 0; r < R_DIM; ++r)
        acc = fmaf(s_w2s[r * 8 + tt], fmaxf(z[r], 0.0f), acc);
    out[b] = acc;
}

extern "C" void kernel_launch(void* const* d_in, const int* in_sizes, int n_in,
                              void* d_out, int out_size, void* d_ws, size_t ws_size,
                              hipStream_t stream) {
    const float* x       = (const float*)d_in[0];
    const int*   t       = (const int*)  d_in[1];
    const float* fw      = (const float*)d_in[2];
    const float* fb      = (const float*)d_in[3];
    const float* f_gamma = (const float*)d_in[4];
    const float* f_beta  = (const float*)d_in[5];
    const float* f_mean  = (const float*)d_in[6];
    const float* f_var   = (const float*)d_in[7];
    const float* tw1     = (const float*)d_in[8];
    const float* tb1     = (const float*)d_in[9];
    const float* t_gamma = (const float*)d_in[10];
    const float* t_beta  = (const float*)d_in[11];
    const float* t_mean  = (const float*)d_in[12];
    const float* t_var   = (const float*)d_in[13];
    const float* tw2     = (const float*)d_in[14];
    const float* tb2     = (const float*)d_in[15];

    float* ws  = (float*)d_ws;
    float* out = (float*)d_out;
    const int B = in_sizes[0] / D_IN;

    tarnet_precompute<<<1, 256, 0, stream>>>(
        f_gamma, f_beta, f_mean, f_var,
        tw1, tb1, t_gamma, t_beta, t_mean, t_var, tw2, tb2, ws);

    const int grid = (B + 255) / 256;
    tarnet_main<<<grid, 256, 0, stream>>>(x, t, fw, fb, ws, out, B);
}

// Round 2
// 74.599 us; speedup vs baseline: 3.1412x; 3.1412x over previous
//
#include <hip/hip_runtime.h>
#include <hip/hip_bf16.h>
#include <cstdint>

#define EPS 1e-5f

typedef short bf16x8 __attribute__((ext_vector_type(8)));
typedef float f32x16 __attribute__((ext_vector_type(16)));

// ws float-offsets
#define WS_TW1S 0       // 16384 ushort (8192 floats): [((t*4+ks)*2+kg)*32 + r]*8 + jj, j = ks*16+kg*8+jj
#define WS_FW   8192    // 8192 ushort (4096 floats): [hc*128 + k]
#define WS_TBW  12288   // 512 floats: float2[t*32+r] = {tb1s, w2s}
#define WS_FB   12800   // 64 floats
#define WS_C2   12864   // 8 floats

static __device__ __forceinline__ unsigned short f2bf(float f) {
    unsigned int u = __float_as_uint(f);
    u += 0x7fffu + ((u >> 16) & 1u);   // round-to-nearest-even
    return (unsigned short)(u >> 16);
}

static __device__ __forceinline__ short f2bf_fast(float f) {
    __hip_bfloat16 b = __float2bfloat16(f);
    return __builtin_bit_cast(short, b);
}

// Fold both eval-mode BNs; emit bf16 weights in MFMA-fragment-native layouts.
__global__ void tarnet_pre(
    const float* __restrict__ fw, const float* __restrict__ fb,
    const float* __restrict__ f_gamma, const float* __restrict__ f_beta,
    const float* __restrict__ f_mean,  const float* __restrict__ f_var,
    const float* __restrict__ tw1, const float* __restrict__ tb1,
    const float* __restrict__ t_gamma, const float* __restrict__ t_beta,
    const float* __restrict__ t_mean,  const float* __restrict__ t_var,
    const float* __restrict__ tw2, const float* __restrict__ tb2,
    float* __restrict__ ws)
{
    __shared__ float fs[64], fsh[64];
    const int i = threadIdx.x;  // 256 threads
    if (i < 64) {
        float s = f_gamma[i] * rsqrtf(f_var[i] + EPS);
        fs[i]  = s;
        fsh[i] = f_beta[i] - f_mean[i] * s;
    }
    __syncthreads();

    unsigned short* tw1s_u = (unsigned short*)(ws + WS_TW1S);
    unsigned short* fw_u   = (unsigned short*)(ws + WS_FW);
    float2*         tbw    = (float2*)(ws + WS_TBW);

    const int t = i >> 5, r = i & 31;
    const int idx = t * 32 + r;
    {
        float tsc  = t_gamma[idx] * rsqrtf(t_var[idx] + EPS);
        float w2s  = tw2[idx] * tsc;
        float tb1s = tb1[idx];
        for (int j = 0; j < 64; ++j) {
            float w = tw1[idx * 64 + j];
            tb1s += w * fsh[j];
            int ks = j >> 4, kg = (j >> 3) & 1, jj = j & 7;
            tw1s_u[(((t*4 + ks)*2 + kg)*32 + r)*8 + jj] = f2bf(w * fs[j]);
        }
        tbw[idx] = make_float2(tb1s, w2s);
    }
    if (r == 0) {  // serial per-head c2 for determinism
        float a = tb2[t];
        for (int rr = 0; rr < 32; ++rr) {
            int id2 = t*32 + rr;
            float ts2 = t_gamma[id2] * rsqrtf(t_var[id2] + EPS);
            a += tw2[id2] * (t_beta[id2] - ts2 * t_mean[id2]);
        }
        ws[WS_C2 + t] = a;
    }
    if (i < 64) {
        for (int k = 0; k < 128; ++k) fw_u[i*128 + k] = f2bf(fw[i*128 + k]);
        ws[WS_FB + i] = fb[i];
    }
}

// 256 threads = 4 waves; 256 samples/block (64/wave). grid = B/256.
__global__ __launch_bounds__(256) void tarnet_main(
    const float* __restrict__ x, const int* __restrict__ t_arr,
    const float* __restrict__ ws, float* __restrict__ out)
{
    __shared__ unsigned short tw1s_lds[16384];   // 32 KB
    __shared__ unsigned short h_lds[256 * 64];   // 32 KB, [s_local][hc] bf16
    __shared__ float2 tbw_lds[256];              // 2 KB
    __shared__ float  fb_lds[64];
    __shared__ float  c2_lds[8];

    const int tid = threadIdx.x;
    {   // stage tables
        const uint4* src = (const uint4*)(ws + WS_TW1S);   // 2048 uint4
        uint4* dst = (uint4*)tw1s_lds;
        for (int k = tid; k < 2048; k += 256) dst[k] = src[k];
        tbw_lds[tid] = ((const float2*)(ws + WS_TBW))[tid];
        if (tid < 64) fb_lds[tid] = ws[WS_FB + tid];
        if (tid < 8)  c2_lds[tid] = ws[WS_C2 + tid];
    }
    __syncthreads();

    const int wave = tid >> 6, lane = tid & 63;
    const int ln31 = lane & 31, hi = lane >> 5;
    const int swave = blockIdx.x * 256 + wave * 64;  // this wave's 64 samples
    const int hbase = wave * 64;                     // wave-private h rows

    const unsigned short* fw_u = (const unsigned short*)(ws + WS_FW);

    // ---------- GEMM1: h = relu(x @ fw^T + fb), bf16 MFMA ----------
    f32x16 acc[2][2];
    {
        float fb0 = fb_lds[ln31], fb1 = fb_lds[32 + ln31];
#pragma unroll
        for (int q = 0; q < 16; ++q) {
            acc[0][0][q] = fb0; acc[0][1][q] = fb1;
            acc[1][0][q] = fb0; acc[1][1][q] = fb1;
        }
    }
#pragma unroll
    for (int ks = 0; ks < 8; ++ks) {
        // B-frags: fw_bf16[hc][k0..7], L1-resident global
        bf16x8 bf0 = *(const bf16x8*)(fw_u + (ln31     )*128 + ks*16 + hi*8);
        bf16x8 bf1 = *(const bf16x8*)(fw_u + (ln31 + 32)*128 + ks*16 + hi*8);
#pragma unroll
        for (int st = 0; st < 2; ++st) {
            const float* xp = x + (size_t)(swave + st*32 + ln31) * 128 + ks*16 + hi*8;
            float4 xa = *(const float4*)xp;
            float4 xb = *(const float4*)(xp + 4);
            bf16x8 af;
            af[0] = f2bf_fast(xa.x); af[1] = f2bf_fast(xa.y);
            af[2] = f2bf_fast(xa.z); af[3] = f2bf_fast(xa.w);
            af[4] = f2bf_fast(xb.x); af[5] = f2bf_fast(xb.y);
            af[6] = f2bf_fast(xb.z); af[7] = f2bf_fast(xb.w);
            acc[st][0] = __builtin_amdgcn_mfma_f32_32x32x16_bf16(af, bf0, acc[st][0], 0, 0, 0);
            acc[st][1] = __builtin_amdgcn_mfma_f32_32x32x16_bf16(af, bf1, acc[st][1], 0, 0, 0);
        }
    }
    // relu + bf16, scatter to wave-private LDS rows (no barrier needed)
#pragma unroll
    for (int st = 0; st < 2; ++st)
#pragma unroll
        for (int nt = 0; nt < 2; ++nt)
#pragma unroll
            for (int q = 0; q < 16; ++q) {
                int row = hbase + st*32 + (q & 3) + ((q >> 2) << 3) + hi*4;
                int col = nt*32 + ln31;
                h_lds[row*64 + col] = (unsigned short)(short)f2bf_fast(fmaxf(acc[st][nt][q], 0.f));
            }

    // ---------- GEMM2^T (dense over 8 heads): z^T = tw1s @ h^T ----------
    // C rows = r (lane&31 over regs), cols = samples (lane&31); one N-row-tile == one head.
    bf16x8 hb[2][4];
#pragma unroll
    for (int st = 0; st < 2; ++st)
#pragma unroll
        for (int ks = 0; ks < 4; ++ks)
            hb[st][ks] = *(const bf16x8*)(h_lds + (hbase + st*32 + ln31)*64 + ks*16 + hi*8);

    const int tsel0 = t_arr[swave + ln31];
    const int tsel1 = t_arr[swave + 32 + ln31];
    float out0 = 0.f, out1 = 0.f;

#pragma unroll 2
    for (int th = 0; th < 8; ++th) {
        bf16x8 aw[4];
#pragma unroll
        for (int ks = 0; ks < 4; ++ks)
            aw[ks] = *(const bf16x8*)(tw1s_lds + (((th*4 + ks)*2 + hi)*32 + ln31)*8);
        float2 tbw[16];
#pragma unroll
        for (int q = 0; q < 16; ++q)
            tbw[q] = tbw_lds[th*32 + (q & 3) + ((q >> 2) << 3) + hi*4];
        const float c2t = c2_lds[th];
#pragma unroll
        for (int st = 0; st < 2; ++st) {
            f32x16 z;
#pragma unroll
            for (int q = 0; q < 16; ++q) z[q] = tbw[q].x;   // tb1s via C-init
            z = __builtin_amdgcn_mfma_f32_32x32x16_bf16(aw[0], hb[st][0], z, 0, 0, 0);
            z = __builtin_amdgcn_mfma_f32_32x32x16_bf16(aw[1], hb[st][1], z, 0, 0, 0);
            z = __builtin_amdgcn_mfma_f32_32x32x16_bf16(aw[2], hb[st][2], z, 0, 0, 0);
            z = __builtin_amdgcn_mfma_f32_32x32x16_bf16(aw[3], hb[st][3], z, 0, 0, 0);
            float p = 0.f;
#pragma unroll
            for (int q = 0; q < 16; ++q)
                p = fmaf(tbw[q].y, fmaxf(z[q], 0.f), p);    // w2s * relu(z)
            p += __shfl_xor(p, 32);                         // sum hi/lo r-halves
            p += c2t;
            if (st == 0) out0 = (th == tsel0) ? p : out0;
            else         out1 = (th == tsel1) ? p : out1;
        }
    }
    out[swave + lane] = hi ? out1 : out0;  // coalesced 64-lane store
}

extern "C" void kernel_launch(void* const* d_in, const int* in_sizes, int n_in,
                              void* d_out, int out_size, void* d_ws, size_t ws_size,
                              hipStream_t stream) {
    const float* x       = (const float*)d_in[0];
    const int*   t       = (const int*)  d_in[1];
    const float* fw      = (const float*)d_in[2];
    const float* fb      = (const float*)d_in[3];
    const float* f_gamma = (const float*)d_in[4];
    const float* f_beta  = (const float*)d_in[5];
    const float* f_mean  = (const float*)d_in[6];
    const float* f_var   = (const float*)d_in[7];
    const float* tw1     = (const float*)d_in[8];
    const float* tb1     = (const float*)d_in[9];
    const float* t_gamma = (const float*)d_in[10];
    const float* t_beta  = (const float*)d_in[11];
    const float* t_mean  = (const float*)d_in[12];
    const float* t_var   = (const float*)d_in[13];
    const float* tw2     = (const float*)d_in[14];
    const float* tb2     = (const float*)d_in[15];

    float* ws  = (float*)d_ws;
    float* outp = (float*)d_out;
    const int B = in_sizes[0] / 128;

    tarnet_pre<<<1, 256, 0, stream>>>(fw, fb, f_gamma, f_beta, f_mean, f_var,
                                      tw1, tb1, t_gamma, t_beta, t_mean, t_var,
                                      tw2, tb2, ws);
    tarnet_main<<<B / 256, 256, 0, stream>>>(x, t, ws, outp);
}

// Round 4
// 63.472 us; speedup vs baseline: 3.6918x; 1.1753x over previous
//
#include <hip/hip_runtime.h>
#include <hip/hip_bf16.h>
#include <cstdint>

#define EPS 1e-5f

typedef short bf16x8 __attribute__((ext_vector_type(8)));
typedef float f32x16 __attribute__((ext_vector_type(16)));
typedef unsigned int u32x4 __attribute__((ext_vector_type(4)));

// ws float-offsets
#define WS_TW1S 0       // 16384 ushort: K-slot-permuted fragment layout (see chi mapping)
#define WS_FW   8192    // 8192 ushort: [hc*128 + k]
#define WS_TB1Q 12288   // 256 floats: [(t*2+hi)*16 + q] fragment-ordered tb1s
#define WS_W2Q  12544   // 256 floats: [(t*2+hi)*16 + q] fragment-ordered w2s
#define WS_FBQ  12800   // 64 floats:  [hi*32 + ht*16 + q] fragment-ordered fb
#define WS_C2   12864   // 8 floats

static __device__ __forceinline__ unsigned short f2bf(float f) {
    unsigned int u = __float_as_uint(f);
    u += 0x7fffu + ((u >> 16) & 1u);   // RNE
    return (unsigned short)(u >> 16);
}
static __device__ __forceinline__ short f2bf_fast(float f) {
    __hip_bfloat16 b = __float2bfloat16(f);
    return __builtin_bit_cast(short, b);
}
static __device__ __forceinline__ unsigned pk_bf16(float lo, float hi) {
    unsigned l = (unsigned)(unsigned short)__builtin_bit_cast(unsigned short, __float2bfloat16(lo));
    unsigned h = (unsigned)(unsigned short)__builtin_bit_cast(unsigned short, __float2bfloat16(hi));
    return l | (h << 16);
}

// Fold both eval-mode BNs; emit bf16 weights + fragment-ordered bias tables.
// tw1s uses the K-slot permutation chi so GEMM2's B-frag is lane-local:
//   channel j = ht*32 + qq*8 + 4h + m  ->  ks = ht*2 + (qq>>1), slot = 8h + (qq&1)*4 + m
__global__ void tarnet_pre(
    const float* __restrict__ fw, const float* __restrict__ fb,
    const float* __restrict__ f_gamma, const float* __restrict__ f_beta,
    const float* __restrict__ f_mean,  const float* __restrict__ f_var,
    const float* __restrict__ tw1, const float* __restrict__ tb1,
    const float* __restrict__ t_gamma, const float* __restrict__ t_beta,
    const float* __restrict__ t_mean,  const float* __restrict__ t_var,
    const float* __restrict__ tw2, const float* __restrict__ tb2,
    float* __restrict__ ws)
{
    __shared__ float fs[64], fsh[64];
    const int i = threadIdx.x;  // 256 threads
    if (i < 64) {
        float s = f_gamma[i] * rsqrtf(f_var[i] + EPS);
        fs[i]  = s;
        fsh[i] = f_beta[i] - f_mean[i] * s;
    }
    __syncthreads();

    unsigned short* tw1s_u = (unsigned short*)(ws + WS_TW1S);
    unsigned short* fw_u   = (unsigned short*)(ws + WS_FW);

    const int t = i >> 5, r = i & 31;
    const int idx = t * 32 + r;
    {
        float tsc  = t_gamma[idx] * rsqrtf(t_var[idx] + EPS);
        float w2s  = tw2[idx] * tsc;
        float tb1s = tb1[idx];
        for (int j = 0; j < 64; ++j) {
            float w = tw1[idx * 64 + j];
            tb1s += w * fsh[j];
            // chi mapping: channel j -> (ks, half h, element ep)
            int ht = j >> 5, qq = (j >> 3) & 3, h = (j >> 2) & 1, m = j & 3;
            int ks = ht * 2 + (qq >> 1);
            int ep = (qq & 1) * 4 + m;
            tw1s_u[(((t*4 + ks)*2 + h)*32 + r)*8 + ep] = f2bf(w * fs[j]);
        }
        // C/D fragment order: r = (q&3) + 8*(q>>2) + 4*hq
        int q  = ((r >> 3) << 2) | (r & 3);
        int hq = (r >> 2) & 1;
        ws[WS_TB1Q + (t*2 + hq)*16 + q] = tb1s;
        ws[WS_W2Q  + (t*2 + hq)*16 + q] = w2s;
    }
    if (r == 0) {
        float a = tb2[t];
        for (int rr = 0; rr < 32; ++rr) {
            int id2 = t*32 + rr;
            float ts2 = t_gamma[id2] * rsqrtf(t_var[id2] + EPS);
            a += tw2[id2] * (t_beta[id2] - ts2 * t_mean[id2]);
        }
        ws[WS_C2 + t] = a;
    }
    if (i < 64) {  // i = hc
        for (int k = 0; k < 128; ++k) fw_u[i*128 + k] = f2bf(fw[i*128 + k]);
        int ht = i >> 5, r32 = i & 31;
        int q  = ((r32 >> 3) << 2) | (r32 & 3);
        int hq = (r32 >> 2) & 1;
        ws[WS_FBQ + hq*32 + ht*16 + q] = fb[i];
    }
}

// 256 threads = 4 independent waves, 64 samples/wave. No LDS, no barriers.
__global__ __launch_bounds__(256) void tarnet_main(
    const float* __restrict__ x, const int* __restrict__ t_arr,
    const float* __restrict__ ws, float* __restrict__ out)
{
    const int tid  = threadIdx.x;
    const int wave = tid >> 6, lane = tid & 63;
    const int ln31 = lane & 31, hi = lane >> 5;
    const int swave = blockIdx.x * 256 + wave * 64;

    const unsigned short* fw_u   = (const unsigned short*)(ws + WS_FW);
    const unsigned short* tw1s_u = (const unsigned short*)(ws + WS_TW1S);

    const int tsel0 = t_arr[swave + ln31];
    const int tsel1 = t_arr[swave + 32 + ln31];

    // ---------- GEMM1: h^T = fw @ x^T (+fb via C-init), rows=hc, cols=samples ----------
    f32x16 acc[2][2];   // [st][ht]
    {
        float fi2[32];
        const float4* fbq4 = (const float4*)(ws + WS_FBQ);
#pragma unroll
        for (int i2 = 0; i2 < 8; ++i2) {
            float4 v = fbq4[hi*8 + i2];
            fi2[i2*4+0] = v.x; fi2[i2*4+1] = v.y; fi2[i2*4+2] = v.z; fi2[i2*4+3] = v.w;
        }
#pragma unroll
        for (int ht = 0; ht < 2; ++ht)
#pragma unroll
            for (int q = 0; q < 16; ++q) {
                acc[0][ht][q] = fi2[ht*16 + q];
                acc[1][ht][q] = fi2[ht*16 + q];
            }
    }
#pragma unroll
    for (int ks = 0; ks < 8; ++ks) {
        // A-frags: fw rows = h channels
        bf16x8 wa0 = *(const bf16x8*)(fw_u + (ln31     )*128 + ks*16 + hi*8);
        bf16x8 wa1 = *(const bf16x8*)(fw_u + (ln31 + 32)*128 + ks*16 + hi*8);
#pragma unroll
        for (int st = 0; st < 2; ++st) {
            const float* xp = x + (size_t)(swave + st*32 + ln31) * 128 + ks*16 + hi*8;
            float4 xa = *(const float4*)xp;
            float4 xb = *(const float4*)(xp + 4);
            bf16x8 xf;  // B-frag: cols = samples
            xf[0] = f2bf_fast(xa.x); xf[1] = f2bf_fast(xa.y);
            xf[2] = f2bf_fast(xa.z); xf[3] = f2bf_fast(xa.w);
            xf[4] = f2bf_fast(xb.x); xf[5] = f2bf_fast(xb.y);
            xf[6] = f2bf_fast(xb.z); xf[7] = f2bf_fast(xb.w);
            acc[st][0] = __builtin_amdgcn_mfma_f32_32x32x16_bf16(wa0, xf, acc[st][0], 0, 0, 0);
            acc[st][1] = __builtin_amdgcn_mfma_f32_32x32x16_bf16(wa1, xf, acc[st][1], 0, 0, 0);
        }
    }

    // ---------- relu -> bf16 pack: GEMM2 B-frags are lane-local under chi ----------
    // acc[st][ht] reg q holds h[channel = ht*32 + (q&3) + 8*(q>>2) + 4*hi][sample = st*32+ln31].
    // chi assigns channel (ht, qq, hi, m) -> tile ks = ht*2+(qq>>1), slot = 8*hi + (qq&1)*4 + m,
    // so B-frag(ks) = {w0[qa], w1[qa], w0[qa+1], w1[qa+1]}, qa = (ks&1)*2 — all own-lane data.
    bf16x8 hb[2][4];    // [st][ks]
#pragma unroll
    for (int st = 0; st < 2; ++st) {
        unsigned w0[2][4], w1[2][4];   // [ht][qq]
#pragma unroll
        for (int ht = 0; ht < 2; ++ht)
#pragma unroll
            for (int qq = 0; qq < 4; ++qq) {
                float a0 = fmaxf(acc[st][ht][qq*4+0], 0.f);
                float a1 = fmaxf(acc[st][ht][qq*4+1], 0.f);
                float a2 = fmaxf(acc[st][ht][qq*4+2], 0.f);
                float a3 = fmaxf(acc[st][ht][qq*4+3], 0.f);
                w0[ht][qq] = pk_bf16(a0, a1);
                w1[ht][qq] = pk_bf16(a2, a3);
            }
#pragma unroll
        for (int ks = 0; ks < 4; ++ks) {
            const int ht = ks >> 1, qa = (ks & 1) * 2;
            u32x4 wv = {w0[ht][qa], w1[ht][qa], w0[ht][qa+1], w1[ht][qa+1]};
            hb[st][ks] = __builtin_bit_cast(bf16x8, wv);
        }
    }

    // ---------- GEMM2 dense over 8 heads: z = tw1s[th] @ h, rows=r, cols=samples ----------
    float out0 = 0.f, out1 = 0.f;
#pragma unroll 2
    for (int th = 0; th < 8; ++th) {
        bf16x8 aw[4];
#pragma unroll
        for (int ks = 0; ks < 4; ++ks)
            aw[ks] = *(const bf16x8*)(tw1s_u + (((th*4 + ks)*2 + hi)*32 + ln31)*8);
        float4 tb4[4];
#pragma unroll
        for (int i2 = 0; i2 < 4; ++i2)
            tb4[i2] = ((const float4*)(ws + WS_TB1Q))[(th*2 + hi)*4 + i2];
        const float c2t = ws[WS_C2 + th];
#pragma unroll
        for (int st = 0; st < 2; ++st) {
            f32x16 z;
#pragma unroll
            for (int q = 0; q < 16; ++q) z[q] = ((const float*)tb4)[q];  // tb1s C-init
            z = __builtin_amdgcn_mfma_f32_32x32x16_bf16(aw[0], hb[st][0], z, 0, 0, 0);
            z = __builtin_amdgcn_mfma_f32_32x32x16_bf16(aw[1], hb[st][1], z, 0, 0, 0);
            z = __builtin_amdgcn_mfma_f32_32x32x16_bf16(aw[2], hb[st][2], z, 0, 0, 0);
            z = __builtin_amdgcn_mfma_f32_32x32x16_bf16(aw[3], hb[st][3], z, 0, 0, 0);
            float4 w24[4];
#pragma unroll
            for (int i2 = 0; i2 < 4; ++i2)
                w24[i2] = ((const float4*)(ws + WS_W2Q))[(th*2 + hi)*4 + i2];
            float p = 0.f;
#pragma unroll
            for (int q = 0; q < 16; ++q)
                p = fmaf(((const float*)w24)[q], fmaxf(z[q], 0.f), p);
            p += __shfl_xor(p, 32);   // other r-half
            p += c2t;
            if (st == 0) out0 = (th == tsel0) ? p : out0;
            else         out1 = (th == tsel1) ? p : out1;
        }
    }
    out[swave + lane] = hi ? out1 : out0;   // coalesced
}

extern "C" void kernel_launch(void* const* d_in, const int* in_sizes, int n_in,
                              void* d_out, int out_size, void* d_ws, size_t ws_size,
                              hipStream_t stream) {
    const float* x       = (const float*)d_in[0];
    const int*   t       = (const int*)  d_in[1];
    const float* fw      = (const float*)d_in[2];
    const float* fb      = (const float*)d_in[3];
    const float* f_gamma = (const float*)d_in[4];
    const float* f_beta  = (const float*)d_in[5];
    const float* f_mean  = (const float*)d_in[6];
    const float* f_var   = (const float*)d_in[7];
    const float* tw1     = (const float*)d_in[8];
    const float* tb1     = (const float*)d_in[9];
    const float* t_gamma = (const float*)d_in[10];
    const float* t_beta  = (const float*)d_in[11];
    const float* t_mean  = (const float*)d_in[12];
    const float* t_var   = (const float*)d_in[13];
    const float* tw2     = (const float*)d_in[14];
    const float* tb2     = (const float*)d_in[15];

    float* ws   = (float*)d_ws;
    float* outp = (float*)d_out;
    const int B = in_sizes[0] / 128;

    tarnet_pre<<<1, 256, 0, stream>>>(fw, fb, f_gamma, f_beta, f_mean, f_var,
                                      tw1, tb1, t_gamma, t_beta, t_mean, t_var,
                                      tw2, tb2, ws);
    tarnet_main<<<B / 256, 256, 0, stream>>>(x, t, ws, outp);
}